// Round 21
// baseline (146.576 us; speedup 1.0000x reference)
//
#include <hip/hip_runtime.h>
#include <math.h>

constexpr int BLK = 256;
constexpr int NBK = 512;         // max coarse buckets (supports N <= 131072)
constexpr int BSHIFT = 8;        // 256 nodes per bucket
constexpr int BSPAN = 1 << BSHIFT;
constexpr int CAP = 5120;        // per-bucket bin capacity (mean 4092 @ E=1.6M, +16 sigma)
constexpr int CAP2 = 8192;       // per-bucket padded col capacity (mean ~4990 + margin)
constexpr int EPT2 = 16;         // edges per thread in binpass
constexpr int EPBB = BLK * EPT2; // 4096 edges per block

typedef unsigned short u16;
typedef __attribute__((ext_vector_type(8))) short short8_t;
typedef __attribute__((ext_vector_type(4))) float f32x4;

// ---- bf16 helpers ----
__device__ __forceinline__ u16 f2bf(float f) {
  union { float f; unsigned int i; } v;
  v.f = f;
  unsigned int r = v.i + 0x7FFF + ((v.i >> 16) & 1);  // RNE
  return (u16)(r >> 16);
}
__device__ __forceinline__ float bf_lo(unsigned u) {
  union { unsigned int i; float f; } v;
  v.i = u << 16;
  return v.f;
}
__device__ __forceinline__ float bf_hi(unsigned u) {
  union { unsigned int i; float f; } v;
  v.i = u & 0xFFFF0000u;
  return v.f;
}

// ---------------- pass 1: coarse binning, block-local sort for coalesced writes ----------------
__global__ void __launch_bounds__(BLK) binpass(const int* __restrict__ src,
                                               const int* __restrict__ dst,
                                               int e, int* __restrict__ bins,
                                               int* __restrict__ tail) {
  __shared__ int lcnt[NBK], lbase[NBK], gbase[NBK], lcur[NBK], sd[BLK];
  __shared__ int stash[EPBB];   // 16KB packed values, bucket-ordered
  __shared__ u16 bkt[EPBB];     // 8KB bucket id per staged word
  const int tid = threadIdx.x;
  lcnt[tid] = 0; lcnt[tid + BLK] = 0;
  lcur[tid] = 0; lcur[tid + BLK] = 0;
  __syncthreads();
  const int i0 = blockIdx.x * EPBB;
  int bb[EPT2], pk[EPT2];
#pragma unroll
  for (int k = 0; k < EPT2; k++) {
    int i = i0 + k * BLK + tid;
    if (i < e) {
      int d = dst[i], s = src[i];
      bb[k] = d >> BSHIFT;
      pk[k] = ((d & (BSPAN - 1)) << 23) | s;   // src < 2^23, dlo < 2^8
      atomicAdd(&lcnt[bb[k]], 1);
    } else {
      bb[k] = -1;
    }
  }
  __syncthreads();
  // block-exclusive scan of lcnt (512 entries, 2 per thread) -> lbase
  int v0 = lcnt[2 * tid], v1 = lcnt[2 * tid + 1], ts = v0 + v1;
  sd[tid] = ts;
  __syncthreads();
  for (int off = 1; off < BLK; off <<= 1) {
    int t = (tid >= off) ? sd[tid - off] : 0;
    __syncthreads();
    sd[tid] += t;
    __syncthreads();
  }
  int ex = sd[tid] - ts;
  lbase[2 * tid] = ex;
  lbase[2 * tid + 1] = ex + v0;
  gbase[2 * tid] = atomicAdd(&tail[2 * tid], v0);
  gbase[2 * tid + 1] = atomicAdd(&tail[2 * tid + 1], v1);
  __syncthreads();
  // stage into stash, bucket-ordered
#pragma unroll
  for (int k = 0; k < EPT2; k++) {
    if (bb[k] >= 0) {
      int idx = atomicAdd(&lcur[bb[k]], 1);
      int pos = lbase[bb[k]] + idx;
      stash[pos] = pk[k];
      bkt[pos] = (u16)bb[k];
    }
  }
  __syncthreads();
  // coalesced write-out: i-order == bucket order
  int total = e - i0;
  if (total > EPBB) total = EPBB;
  for (int i = tid; i < total; i += BLK) {
    int b = bkt[i];
    bins[b * CAP + gbase[b] + (i - lbase[b])] = stash[i];
  }
}

// ---------------- pass 2: per-bucket counting sort into FIXED col region ----------------
// Also emits perm: nodes of each bucket ordered by ascending nb (trip count),
// so agg waves get uniform trip counts (kills exec-mask divergence tax).
__global__ void __launch_bounds__(BLK) bucket_sort(const int* __restrict__ bins,
                                                   const int* __restrict__ tail,
                                                   unsigned* __restrict__ wdesc,
                                                   int* __restrict__ col,
                                                   float* __restrict__ dinv,
                                                   int* __restrict__ perm, int n) {
  __shared__ int hist[BSPAN], lpre[BSPAN], lcur[BSPAN], sd[BLK];
  __shared__ int nbh[32], nboff[32];
  const int b = blockIdx.x, tid = threadIdx.x;
  const int cnt = tail[b];
  const int base = b * CAP2;
  const int node0 = b << BSHIFT;
  const int nNodes = min(BSPAN, n - node0);
  const int* bin = bins + (size_t)b * CAP;

  hist[tid] = 0;
  lcur[tid] = 0;
  if (tid < 32) nbh[tid] = 0;
  __syncthreads();
  for (int j = tid; j < cnt; j += BLK) atomicAdd(&hist[(unsigned)bin[j] >> 23], 1);
  __syncthreads();
  // exclusive scan over PADDED counts (1 per thread)
  int h0 = hist[tid];
  int p0 = (h0 + 7) & ~7;
  sd[tid] = p0;
  __syncthreads();
  for (int off = 1; off < BLK; off <<= 1) {
    int t = (tid >= off) ? sd[tid - off] : 0;
    __syncthreads();
    sd[tid] += t;
    __syncthreads();
  }
  lpre[tid] = sd[tid] - p0;
  __syncthreads();
  int mynb = -1;
  if (tid < nNodes) {
    int begd = base + lpre[tid];
    mynb = (h0 + 7) >> 3;
    wdesc[node0 + tid] = ((unsigned)begd << 10) | (unsigned)mynb;
    dinv[node0 + tid] = rsqrtf((float)h0 + 1.0f);
    int pe = (h0 + 7) & ~7;
    for (int t = h0; t < pe; t++) col[begd + t] = n;  // pad -> zero row
    if (mynb > 31) mynb = 31;
    atomicAdd(&nbh[mynb], 1);
  }
  __syncthreads();
  if (tid == 0) {
    int acc = 0;
    for (int i = 0; i < 32; i++) { nboff[i] = acc; acc += nbh[i]; }
  }
  __syncthreads();
  if (mynb >= 0) {
    int r = atomicAdd(&nboff[mynb], 1);
    perm[node0 + r] = node0 + tid;   // bucket slots are contiguous in gid space
  }
  __syncthreads();
  for (int j = tid; j < cnt; j += BLK) {
    int pkv = bin[j];
    int dlo = (unsigned)pkv >> 23;
    int idx = atomicAdd(&lcur[dlo], 1);
    col[base + lpre[dlo] + idx] = pkv & 0x7FFFFF;
  }
}

// ---------------- MFMA GEMM via split-bf16: G = bf16((X @ W) * dinv) ----------------
template <int K, int M, int RT>
__global__ void __launch_bounds__(BLK) gemm_mfma(const float* __restrict__ X,
                                                 const float* __restrict__ W,
                                                 const float* __restrict__ dinv,
                                                 u16* __restrict__ G, int n) {
  constexpr int KC = K / 32;   // K-chunks
  constexpr int CT = M / 16;   // 16-col tiles
  constexpr int PADK = K + 8;  // row stride 272B (K=128): 2-way bank alias = free
  __shared__ u16 wt_hi[M][PADK];
  __shared__ u16 wt_lo[M][PADK];
  const int tid = threadIdx.x;
  const int lane = tid & 63;
  const int wv = tid >> 6;

  if (blockIdx.x == 0 && tid < M) G[(size_t)n * M + tid] = 0;  // zero pad row

  // stage W transposed + hi/lo split (one-time; reads coalesced)
  for (int i = tid; i < K * M; i += BLK) {
    int k = i / M, m = i % M;
    float w = W[i];
    unsigned wb = __float_as_uint(w);
    wt_hi[m][k] = (u16)(wb >> 16);                       // truncation hi
    wt_lo[m][k] = f2bf(w - __uint_as_float(wb & 0xFFFF0000u));
  }
  __syncthreads();

  const int r16 = lane & 15;
  const int oct = lane >> 4;

#pragma unroll
  for (int rt = 0; rt < RT; rt++) {
    int rowA = blockIdx.x * (64 * RT) + rt * 64 + wv * 16 + r16;
    if (rowA >= n) rowA = n - 1;  // clamp (stores guarded)

    f32x4 acc[CT];
#pragma unroll
    for (int ct = 0; ct < CT; ct++) acc[ct] = (f32x4){0.f, 0.f, 0.f, 0.f};

#pragma unroll
    for (int kc = 0; kc < KC; kc++) {
      const float* xp = &X[(size_t)rowA * K + kc * 32 + oct * 8];
      float4 v0 = *(const float4*)xp;
      float4 v1 = *(const float4*)(xp + 4);
      float vv[8] = {v0.x, v0.y, v0.z, v0.w, v1.x, v1.y, v1.z, v1.w};
      short8_t ahi, alo;
#pragma unroll
      for (int j = 0; j < 8; j++) {
        unsigned xb = __float_as_uint(vv[j]);
        ahi[j] = (short)(xb >> 16);  // truncation hi
        alo[j] = (short)f2bf(vv[j] - __uint_as_float(xb & 0xFFFF0000u));
      }
#pragma unroll
      for (int ct = 0; ct < CT; ct++) {
        short8_t bhi = *(const short8_t*)&wt_hi[ct * 16 + r16][kc * 32 + oct * 8];
        short8_t blo = *(const short8_t*)&wt_lo[ct * 16 + r16][kc * 32 + oct * 8];
        acc[ct] = __builtin_amdgcn_mfma_f32_16x16x32_bf16(ahi, bhi, acc[ct], 0, 0, 0);
        acc[ct] = __builtin_amdgcn_mfma_f32_16x16x32_bf16(alo, bhi, acc[ct], 0, 0, 0);
        acc[ct] = __builtin_amdgcn_mfma_f32_16x16x32_bf16(ahi, blo, acc[ct], 0, 0, 0);
      }
    }

    // epilogue: C row = oct*4 + reg, col = ct*16 + r16
    const int rbase = blockIdx.x * (64 * RT) + rt * 64 + wv * 16 + oct * 4;
    float dv[4];
#pragma unroll
    for (int r = 0; r < 4; r++) {
      int gr = rbase + r;
      dv[r] = (gr < n) ? dinv[gr] : 0.f;
    }
#pragma unroll
    for (int ct = 0; ct < CT; ct++) {
#pragma unroll
      for (int r = 0; r < 4; r++) {
        int gr = rbase + r;
        if (gr < n) G[(size_t)gr * M + ct * 16 + r16] = f2bf(acc[ct][r] * dv[r]);
      }
    }
  }
}

// ---------------- aggregation (one node per lane-group, degree-sorted perm) ----------------
// gs (bf16, N+1 rows; row n zero). Segments padded to mult-of-8 with col=n.

#define ADD8(u)                                                         \
  a0 += bf_lo(u.x); a1 += bf_hi(u.x); a2 += bf_lo(u.y); a3 += bf_hi(u.y); \
  a4 += bf_lo(u.z); a5 += bf_hi(u.z); a6 += bf_lo(u.w); a7 += bf_hi(u.w);

__global__ void __launch_bounds__(BLK) agg1_kernel(const u16* __restrict__ gs,
                                                   const unsigned* __restrict__ wdesc,
                                                   const int* __restrict__ col,
                                                   const float* __restrict__ dinv,
                                                   const float* __restrict__ bias,
                                                   const int* __restrict__ perm,
                                                   float* __restrict__ out, int n) {
  const int tid = threadIdx.x;
  const int gid = blockIdx.x * 32 + (tid >> 3);
  if (gid >= n) return;
  const int node = perm[gid];
  const int cs = tid & 7;
  unsigned w = wdesc[node];
  int beg = (int)(w >> 10), nb = (int)(w & 1023);
  float a0, a1, a2, a3, a4, a5, a6, a7;
  {  // self-loop slice
    uint4 u = *(const uint4*)&gs[(size_t)node * 64 + cs * 8];
    a0 = bf_lo(u.x); a1 = bf_hi(u.x); a2 = bf_lo(u.y); a3 = bf_hi(u.y);
    a4 = bf_lo(u.z); a5 = bf_hi(u.z); a6 = bf_lo(u.w); a7 = bf_hi(u.w);
  }
  for (int i = 0; i < nb; i++) {
    int j = beg + i * 8;
    int4 sA = *(const int4*)&col[j];
    int4 sB = *(const int4*)&col[j + 4];
    uint4 u0 = *(const uint4*)&gs[(size_t)sA.x * 64 + cs * 8];
    uint4 u1 = *(const uint4*)&gs[(size_t)sA.y * 64 + cs * 8];
    uint4 u2 = *(const uint4*)&gs[(size_t)sA.z * 64 + cs * 8];
    uint4 u3 = *(const uint4*)&gs[(size_t)sA.w * 64 + cs * 8];
    uint4 u4 = *(const uint4*)&gs[(size_t)sB.x * 64 + cs * 8];
    uint4 u5 = *(const uint4*)&gs[(size_t)sB.y * 64 + cs * 8];
    uint4 u6 = *(const uint4*)&gs[(size_t)sB.z * 64 + cs * 8];
    uint4 u7 = *(const uint4*)&gs[(size_t)sB.w * 64 + cs * 8];
    ADD8(u0) ADD8(u1) ADD8(u2) ADD8(u3)
    ADD8(u4) ADD8(u5) ADD8(u6) ADD8(u7)
  }
  float di = dinv[node];
  float4 bv0 = *(const float4*)&bias[cs * 8];
  float4 bv1 = *(const float4*)&bias[cs * 8 + 4];
  float4 o0, o1;
  o0.x = a0 * di + bv0.x; o0.y = a1 * di + bv0.y;
  o0.z = a2 * di + bv0.z; o0.w = a3 * di + bv0.w;
  o1.x = a4 * di + bv1.x; o1.y = a5 * di + bv1.y;
  o1.z = a6 * di + bv1.z; o1.w = a7 * di + bv1.w;
  o0.x = o0.x > 0.f ? o0.x : 0.f; o0.y = o0.y > 0.f ? o0.y : 0.f;
  o0.z = o0.z > 0.f ? o0.z : 0.f; o0.w = o0.w > 0.f ? o0.w : 0.f;
  o1.x = o1.x > 0.f ? o1.x : 0.f; o1.y = o1.y > 0.f ? o1.y : 0.f;
  o1.z = o1.z > 0.f ? o1.z : 0.f; o1.w = o1.w > 0.f ? o1.w : 0.f;
  *(float4*)&out[(size_t)node * 64 + cs * 8] = o0;
  *(float4*)&out[(size_t)node * 64 + cs * 8 + 4] = o1;
}

__global__ void __launch_bounds__(BLK) agg2_kernel(const u16* __restrict__ gs,
                                                   const unsigned* __restrict__ wdesc,
                                                   const int* __restrict__ col,
                                                   const float* __restrict__ dinv,
                                                   const float* __restrict__ bias,
                                                   const int* __restrict__ perm,
                                                   float* __restrict__ out, int n) {
  const int tid = threadIdx.x;
  const int gid = blockIdx.x * 64 + (tid >> 2);
  if (gid >= n) return;
  const int node = perm[gid];
  const int cs = tid & 3;
  unsigned w = wdesc[node];
  int beg = (int)(w >> 10), nb = (int)(w & 1023);
  float a0, a1, a2, a3, a4, a5, a6, a7;
  {
    uint4 u = *(const uint4*)&gs[(size_t)node * 32 + cs * 8];
    a0 = bf_lo(u.x); a1 = bf_hi(u.x); a2 = bf_lo(u.y); a3 = bf_hi(u.y);
    a4 = bf_lo(u.z); a5 = bf_hi(u.z); a6 = bf_lo(u.w); a7 = bf_hi(u.w);
  }
  for (int i = 0; i < nb; i++) {
    int j = beg + i * 8;
    int4 sA = *(const int4*)&col[j];
    int4 sB = *(const int4*)&col[j + 4];
    uint4 u0 = *(const uint4*)&gs[(size_t)sA.x * 32 + cs * 8];
    uint4 u1 = *(const uint4*)&gs[(size_t)sA.y * 32 + cs * 8];
    uint4 u2 = *(const uint4*)&gs[(size_t)sA.z * 32 + cs * 8];
    uint4 u3 = *(const uint4*)&gs[(size_t)sA.w * 32 + cs * 8];
    uint4 u4 = *(const uint4*)&gs[(size_t)sB.x * 32 + cs * 8];
    uint4 u5 = *(const uint4*)&gs[(size_t)sB.y * 32 + cs * 8];
    uint4 u6 = *(const uint4*)&gs[(size_t)sB.z * 32 + cs * 8];
    uint4 u7 = *(const uint4*)&gs[(size_t)sB.w * 32 + cs * 8];
    ADD8(u0) ADD8(u1) ADD8(u2) ADD8(u3)
    ADD8(u4) ADD8(u5) ADD8(u6) ADD8(u7)
  }
  float di = dinv[node];
  float4 bv0 = *(const float4*)&bias[cs * 8];
  float4 bv1 = *(const float4*)&bias[cs * 8 + 4];
  float4 o0, o1;
  o0.x = a0 * di + bv0.x; o0.y = a1 * di + bv0.y;
  o0.z = a2 * di + bv0.z; o0.w = a3 * di + bv0.w;
  o1.x = a4 * di + bv1.x; o1.y = a5 * di + bv1.y;
  o1.z = a6 * di + bv1.z; o1.w = a7 * di + bv1.w;
  o0.x = o0.x > 0.f ? o0.x : 0.f; o0.y = o0.y > 0.f ? o0.y : 0.f;
  o0.z = o0.z > 0.f ? o0.z : 0.f; o0.w = o0.w > 0.f ? o0.w : 0.f;
  o1.x = o1.x > 0.f ? o1.x : 0.f; o1.y = o1.y > 0.f ? o1.y : 0.f;
  o1.z = o1.z > 0.f ? o1.z : 0.f; o1.w = o1.w > 0.f ? o1.w : 0.f;
  *(float4*)&out[(size_t)node * 32 + cs * 8] = o0;
  *(float4*)&out[(size_t)node * 32 + cs * 8 + 4] = o1;
}

// ---------------- launcher ----------------

extern "C" void kernel_launch(void* const* d_in, const int* in_sizes, int n_in,
                              void* d_out, int out_size, void* d_ws, size_t ws_size,
                              hipStream_t stream) {
  const float* x = (const float*)d_in[0];
  const int* ei = (const int*)d_in[1];
  const float* W1 = (const float*)d_in[2];
  const float* b1 = (const float*)d_in[3];
  const float* W2 = (const float*)d_in[4];
  const float* b2 = (const float*)d_in[5];

  const int N = in_sizes[0] / 128;
  const int E = in_sizes[1] / 2;
  const int* src = ei;
  const int* dst = ei + E;
  const int nb = (N + BSPAN - 1) >> BSHIFT;  // # coarse buckets (391 @ N=100K)

  char* p = (char*)d_ws;
  auto take = [&](size_t bytes) -> char* {
    char* q = p;
    p += (bytes + 255) & ~(size_t)255;
    return q;
  };
  int* bins = (int*)take((size_t)NBK * CAP * 4);
  int* tail = (int*)take(NBK * 4);
  unsigned* wdesc = (unsigned*)take((size_t)N * 4);
  int* col = (int*)take((size_t)nb * CAP2 * 4);
  float* dinv = (float*)take((size_t)N * 4);
  int* perm = (int*)take((size_t)N * 4);
  u16* g1 = (u16*)take((size_t)(N + 1) * 64 * 2);  // +1 zero row
  float* h = (float*)take((size_t)N * 64 * 4);
  u16* g2 = (u16*)take((size_t)(N + 1) * 32 * 2);  // +1 zero row

  hipMemsetAsync(tail, 0, NBK * 4, stream);

  binpass<<<(E + EPBB - 1) / EPBB, BLK, 0, stream>>>(src, dst, E, bins, tail);
  bucket_sort<<<nb, BLK, 0, stream>>>(bins, tail, wdesc, col, dinv, perm, N);

  gemm_mfma<128, 64, 2><<<(N + 127) / 128, BLK, 0, stream>>>(x, W1, dinv, g1, N);
  agg1_kernel<<<(N + 31) / 32, BLK, 0, stream>>>(g1, wdesc, col, dinv, b1, perm, h, N);
  gemm_mfma<64, 32, 1><<<(N + 63) / 64, BLK, 0, stream>>>(h, W2, dinv, g2, N);
  agg2_kernel<<<(N + 63) / 64, BLK, 0, stream>>>(g2, wdesc, col, dinv, b2, perm, (float*)d_out, N);
}

// Round 22
// 135.485 us; speedup vs baseline: 1.0819x; 1.0819x over previous
//
#include <hip/hip_runtime.h>
#include <math.h>

constexpr int BLK = 256;
constexpr int NB_MAX = 256;      // max coarse buckets (supports N <= 131072)
constexpr int BSHIFT = 9;        // 512 nodes per bucket
constexpr int BSPAN = 1 << BSHIFT;
constexpr int CAP = 10240;       // per-bucket bin capacity (mean 8192 @ E=1.6M, +22 sigma)
constexpr int CAP2 = 12800;      // per-bucket padded col capacity (mean 9984, +31 sigma)
constexpr int EPT2 = 16;         // edges per thread in binpass
constexpr int EPBB = BLK * EPT2; // 4096 edges per block

typedef unsigned short u16;
typedef __attribute__((ext_vector_type(8))) short short8_t;
typedef __attribute__((ext_vector_type(4))) float f32x4;

// ---- bf16 helpers ----
__device__ __forceinline__ u16 f2bf(float f) {
  union { float f; unsigned int i; } v;
  v.f = f;
  unsigned int r = v.i + 0x7FFF + ((v.i >> 16) & 1);  // RNE
  return (u16)(r >> 16);
}
__device__ __forceinline__ float bf_lo(unsigned u) {
  union { unsigned int i; float f; } v;
  v.i = u << 16;
  return v.f;
}
__device__ __forceinline__ float bf_hi(unsigned u) {
  union { unsigned int i; float f; } v;
  v.i = u & 0xFFFF0000u;
  return v.f;
}

// ---------------- pass 1: coarse binning, block-local sort for coalesced writes ----------------
__global__ void __launch_bounds__(BLK) binpass(const int* __restrict__ src,
                                               const int* __restrict__ dst,
                                               int e, int* __restrict__ bins,
                                               int* __restrict__ tail) {
  __shared__ int lcnt[NB_MAX], lbase[NB_MAX], gbase[NB_MAX], lcur[NB_MAX], sd[BLK];
  __shared__ int stash[EPBB];   // 16KB packed values, bucket-ordered
  __shared__ u16 bkt[EPBB];     // 8KB bucket id per staged word
  const int tid = threadIdx.x;
  lcnt[tid] = 0;
  lcur[tid] = 0;
  __syncthreads();
  const int i0 = blockIdx.x * EPBB;
  int bb[EPT2], pk[EPT2];
#pragma unroll
  for (int k = 0; k < EPT2; k++) {
    int i = i0 + k * BLK + tid;
    if (i < e) {
      int d = dst[i], s = src[i];
      bb[k] = d >> BSHIFT;
      pk[k] = ((d & (BSPAN - 1)) << 23) | s;   // src < 2^23, dlo < 2^9
      atomicAdd(&lcnt[bb[k]], 1);
    } else {
      bb[k] = -1;
    }
  }
  __syncthreads();
  // block-exclusive scan of lcnt -> lbase; reserve global chunk per bucket
  int v = lcnt[tid];
  sd[tid] = v;
  __syncthreads();
  for (int off = 1; off < BLK; off <<= 1) {
    int t = (tid >= off) ? sd[tid - off] : 0;
    __syncthreads();
    sd[tid] += t;
    __syncthreads();
  }
  lbase[tid] = sd[tid] - v;
  gbase[tid] = atomicAdd(&tail[tid], v);
  __syncthreads();
  // stage into stash, bucket-ordered
#pragma unroll
  for (int k = 0; k < EPT2; k++) {
    if (bb[k] >= 0) {
      int idx = atomicAdd(&lcur[bb[k]], 1);
      int pos = lbase[bb[k]] + idx;
      stash[pos] = pk[k];
      bkt[pos] = (u16)bb[k];
    }
  }
  __syncthreads();
  // coalesced write-out: i-order == bucket order
  int total = e - i0;
  if (total > EPBB) total = EPBB;
  for (int i = tid; i < total; i += BLK) {
    int b = bkt[i];
    bins[b * CAP + gbase[b] + (i - lbase[b])] = stash[i];
  }
}

// ---------------- pass 2: per-bucket counting sort into FIXED col region ----------------
__global__ void __launch_bounds__(BLK) bucket_sort(const int* __restrict__ bins,
                                                   const int* __restrict__ tail,
                                                   unsigned* __restrict__ wdesc,
                                                   int* __restrict__ col,
                                                   float* __restrict__ dinv, int n) {
  __shared__ int hist[BSPAN], lpre[BSPAN], lcur[BSPAN], sd[BLK];
  const int b = blockIdx.x, tid = threadIdx.x;
  const int cnt = tail[b];
  const int base = b * CAP2;
  const int node0 = b << BSHIFT;
  const int nNodes = min(BSPAN, n - node0);
  const int* bin = bins + (size_t)b * CAP;

  hist[tid] = 0; hist[tid + BLK] = 0;
  lcur[tid] = 0; lcur[tid + BLK] = 0;
  __syncthreads();
  for (int j = tid; j < cnt; j += BLK) atomicAdd(&hist[(unsigned)bin[j] >> 23], 1);
  __syncthreads();
  // exclusive scan over PADDED counts (2 per thread)
  int h0 = hist[2 * tid], h1 = hist[2 * tid + 1];
  int p0 = (h0 + 7) & ~7, p1 = (h1 + 7) & ~7;
  int ts = p0 + p1;
  sd[tid] = ts;
  __syncthreads();
  for (int off = 1; off < BLK; off <<= 1) {
    int t = (tid >= off) ? sd[tid - off] : 0;
    __syncthreads();
    sd[tid] += t;
    __syncthreads();
  }
  int ex = sd[tid] - ts;
  lpre[2 * tid] = ex;
  lpre[2 * tid + 1] = ex + p0;
  __syncthreads();
  for (int d = tid; d < nNodes; d += BLK) {
    int hd = hist[d];
    int begd = base + lpre[d];
    wdesc[node0 + d] = ((unsigned)begd << 10) | (unsigned)((hd + 7) >> 3);
    dinv[node0 + d] = rsqrtf((float)hd + 1.0f);
    int pe = (hd + 7) & ~7;
    for (int t = hd; t < pe; t++) col[begd + t] = n;  // pad -> zero row
  }
  __syncthreads();
  for (int j = tid; j < cnt; j += BLK) {
    int pkv = bin[j];
    int dlo = (unsigned)pkv >> 23;
    int idx = atomicAdd(&lcur[dlo], 1);
    col[base + lpre[dlo] + idx] = pkv & 0x7FFFFF;
  }
}

// ---------------- MFMA GEMM via split-bf16: G = bf16((X @ W) * dinv) ----------------
template <int K, int M, int RT>
__global__ void __launch_bounds__(BLK) gemm_mfma(const float* __restrict__ X,
                                                 const float* __restrict__ W,
                                                 const float* __restrict__ dinv,
                                                 u16* __restrict__ G, int n) {
  constexpr int KC = K / 32;   // K-chunks
  constexpr int CT = M / 16;   // 16-col tiles
  constexpr int PADK = K + 8;  // row stride 272B (K=128): 2-way bank alias = free
  __shared__ u16 wt_hi[M][PADK];
  __shared__ u16 wt_lo[M][PADK];
  const int tid = threadIdx.x;
  const int lane = tid & 63;
  const int wv = tid >> 6;

  if (blockIdx.x == 0 && tid < M) G[(size_t)n * M + tid] = 0;  // zero pad row

  // stage W transposed + hi/lo split (one-time; reads coalesced)
  for (int i = tid; i < K * M; i += BLK) {
    int k = i / M, m = i % M;
    float w = W[i];
    unsigned wb = __float_as_uint(w);
    wt_hi[m][k] = (u16)(wb >> 16);                       // truncation hi
    wt_lo[m][k] = f2bf(w - __uint_as_float(wb & 0xFFFF0000u));
  }
  __syncthreads();

  const int r16 = lane & 15;
  const int oct = lane >> 4;

#pragma unroll
  for (int rt = 0; rt < RT; rt++) {
    int rowA = blockIdx.x * (64 * RT) + rt * 64 + wv * 16 + r16;
    if (rowA >= n) rowA = n - 1;  // clamp (stores guarded)

    f32x4 acc[CT];
#pragma unroll
    for (int ct = 0; ct < CT; ct++) acc[ct] = (f32x4){0.f, 0.f, 0.f, 0.f};

#pragma unroll
    for (int kc = 0; kc < KC; kc++) {
      const float* xp = &X[(size_t)rowA * K + kc * 32 + oct * 8];
      float4 v0 = *(const float4*)xp;
      float4 v1 = *(const float4*)(xp + 4);
      float vv[8] = {v0.x, v0.y, v0.z, v0.w, v1.x, v1.y, v1.z, v1.w};
      short8_t ahi, alo;
#pragma unroll
      for (int j = 0; j < 8; j++) {
        unsigned xb = __float_as_uint(vv[j]);
        ahi[j] = (short)(xb >> 16);  // truncation hi
        alo[j] = (short)f2bf(vv[j] - __uint_as_float(xb & 0xFFFF0000u));
      }
#pragma unroll
      for (int ct = 0; ct < CT; ct++) {
        short8_t bhi = *(const short8_t*)&wt_hi[ct * 16 + r16][kc * 32 + oct * 8];
        short8_t blo = *(const short8_t*)&wt_lo[ct * 16 + r16][kc * 32 + oct * 8];
        acc[ct] = __builtin_amdgcn_mfma_f32_16x16x32_bf16(ahi, bhi, acc[ct], 0, 0, 0);
        acc[ct] = __builtin_amdgcn_mfma_f32_16x16x32_bf16(alo, bhi, acc[ct], 0, 0, 0);
        acc[ct] = __builtin_amdgcn_mfma_f32_16x16x32_bf16(ahi, blo, acc[ct], 0, 0, 0);
      }
    }

    // epilogue: C row = oct*4 + reg, col = ct*16 + r16
    const int rbase = blockIdx.x * (64 * RT) + rt * 64 + wv * 16 + oct * 4;
    float dv[4];
#pragma unroll
    for (int r = 0; r < 4; r++) {
      int gr = rbase + r;
      dv[r] = (gr < n) ? dinv[gr] : 0.f;
    }
#pragma unroll
    for (int ct = 0; ct < CT; ct++) {
#pragma unroll
      for (int r = 0; r < 4; r++) {
        int gr = rbase + r;
        if (gr < n) G[(size_t)gr * M + ct * 16 + r16] = f2bf(acc[ct][r] * dv[r]);
      }
    }
  }
}

// ---------------- aggregation (one node per lane-group, no shuffles) ----------------
// gs (bf16, N+1 rows; row n zero). Segments padded to mult-of-8 with col=n.

// layer 1: 16 lanes per node (cs = 4-channel slice). Per iter: 2 broadcast int4
// col loads + 8 row gathers (128B line each) + 32 unpack-adds per lane.
__global__ void __launch_bounds__(BLK) agg1_kernel(const u16* __restrict__ gs,
                                                   const unsigned* __restrict__ wdesc,
                                                   const int* __restrict__ col,
                                                   const float* __restrict__ dinv,
                                                   const float* __restrict__ bias,
                                                   float* __restrict__ out, int n) {
  const int tid = threadIdx.x;
  const int node = blockIdx.x * 16 + (tid >> 4);
  if (node >= n) return;
  const int cs = tid & 15;
  unsigned w = wdesc[node];
  int beg = (int)(w >> 10), nb = (int)(w & 1023);
  float a0, a1, a2, a3;
  {  // self-loop slice (unconditional: this group owns the node)
    uint2 u = *(const uint2*)&gs[(size_t)node * 64 + cs * 4];
    a0 = bf_lo(u.x); a1 = bf_hi(u.x); a2 = bf_lo(u.y); a3 = bf_hi(u.y);
  }
  for (int i = 0; i < nb; i++) {
    int j = beg + i * 8;
    int4 sA = *(const int4*)&col[j];
    int4 sB = *(const int4*)&col[j + 4];
    uint2 u0 = *(const uint2*)&gs[(size_t)sA.x * 64 + cs * 4];
    uint2 u1 = *(const uint2*)&gs[(size_t)sA.y * 64 + cs * 4];
    uint2 u2 = *(const uint2*)&gs[(size_t)sA.z * 64 + cs * 4];
    uint2 u3 = *(const uint2*)&gs[(size_t)sA.w * 64 + cs * 4];
    uint2 u4 = *(const uint2*)&gs[(size_t)sB.x * 64 + cs * 4];
    uint2 u5 = *(const uint2*)&gs[(size_t)sB.y * 64 + cs * 4];
    uint2 u6 = *(const uint2*)&gs[(size_t)sB.z * 64 + cs * 4];
    uint2 u7 = *(const uint2*)&gs[(size_t)sB.w * 64 + cs * 4];
    a0 += bf_lo(u0.x); a1 += bf_hi(u0.x); a2 += bf_lo(u0.y); a3 += bf_hi(u0.y);
    a0 += bf_lo(u1.x); a1 += bf_hi(u1.x); a2 += bf_lo(u1.y); a3 += bf_hi(u1.y);
    a0 += bf_lo(u2.x); a1 += bf_hi(u2.x); a2 += bf_lo(u2.y); a3 += bf_hi(u2.y);
    a0 += bf_lo(u3.x); a1 += bf_hi(u3.x); a2 += bf_lo(u3.y); a3 += bf_hi(u3.y);
    a0 += bf_lo(u4.x); a1 += bf_hi(u4.x); a2 += bf_lo(u4.y); a3 += bf_hi(u4.y);
    a0 += bf_lo(u5.x); a1 += bf_hi(u5.x); a2 += bf_lo(u5.y); a3 += bf_hi(u5.y);
    a0 += bf_lo(u6.x); a1 += bf_hi(u6.x); a2 += bf_lo(u6.y); a3 += bf_hi(u6.y);
    a0 += bf_lo(u7.x); a1 += bf_hi(u7.x); a2 += bf_lo(u7.y); a3 += bf_hi(u7.y);
  }
  float di = dinv[node];
  float4 bv = *(const float4*)&bias[cs * 4];
  float4 o;
  o.x = a0 * di + bv.x; o.y = a1 * di + bv.y;
  o.z = a2 * di + bv.z; o.w = a3 * di + bv.w;
  o.x = o.x > 0.f ? o.x : 0.f;
  o.y = o.y > 0.f ? o.y : 0.f;
  o.z = o.z > 0.f ? o.z : 0.f;
  o.w = o.w > 0.f ? o.w : 0.f;
  *(float4*)&out[(size_t)node * 64 + cs * 4] = o;
}

// layer 2: 8 lanes per node (cs = 4-channel slice of 32). Same batch structure.
__global__ void __launch_bounds__(BLK) agg2_kernel(const u16* __restrict__ gs,
                                                   const unsigned* __restrict__ wdesc,
                                                   const int* __restrict__ col,
                                                   const float* __restrict__ dinv,
                                                   const float* __restrict__ bias,
                                                   float* __restrict__ out, int n) {
  const int tid = threadIdx.x;
  const int node = blockIdx.x * 32 + (tid >> 3);
  if (node >= n) return;
  const int cs = tid & 7;
  unsigned w = wdesc[node];
  int beg = (int)(w >> 10), nb = (int)(w & 1023);
  float a0, a1, a2, a3;
  {
    uint2 u = *(const uint2*)&gs[(size_t)node * 32 + cs * 4];
    a0 = bf_lo(u.x); a1 = bf_hi(u.x); a2 = bf_lo(u.y); a3 = bf_hi(u.y);
  }
  for (int i = 0; i < nb; i++) {
    int j = beg + i * 8;
    int4 sA = *(const int4*)&col[j];
    int4 sB = *(const int4*)&col[j + 4];
    uint2 u0 = *(const uint2*)&gs[(size_t)sA.x * 32 + cs * 4];
    uint2 u1 = *(const uint2*)&gs[(size_t)sA.y * 32 + cs * 4];
    uint2 u2 = *(const uint2*)&gs[(size_t)sA.z * 32 + cs * 4];
    uint2 u3 = *(const uint2*)&gs[(size_t)sA.w * 32 + cs * 4];
    uint2 u4 = *(const uint2*)&gs[(size_t)sB.x * 32 + cs * 4];
    uint2 u5 = *(const uint2*)&gs[(size_t)sB.y * 32 + cs * 4];
    uint2 u6 = *(const uint2*)&gs[(size_t)sB.z * 32 + cs * 4];
    uint2 u7 = *(const uint2*)&gs[(size_t)sB.w * 32 + cs * 4];
    a0 += bf_lo(u0.x); a1 += bf_hi(u0.x); a2 += bf_lo(u0.y); a3 += bf_hi(u0.y);
    a0 += bf_lo(u1.x); a1 += bf_hi(u1.x); a2 += bf_lo(u1.y); a3 += bf_hi(u1.y);
    a0 += bf_lo(u2.x); a1 += bf_hi(u2.x); a2 += bf_lo(u2.y); a3 += bf_hi(u2.y);
    a0 += bf_lo(u3.x); a1 += bf_hi(u3.x); a2 += bf_lo(u3.y); a3 += bf_hi(u3.y);
    a0 += bf_lo(u4.x); a1 += bf_hi(u4.x); a2 += bf_lo(u4.y); a3 += bf_hi(u4.y);
    a0 += bf_lo(u5.x); a1 += bf_hi(u5.x); a2 += bf_lo(u5.y); a3 += bf_hi(u5.y);
    a0 += bf_lo(u6.x); a1 += bf_hi(u6.x); a2 += bf_lo(u6.y); a3 += bf_hi(u6.y);
    a0 += bf_lo(u7.x); a1 += bf_hi(u7.x); a2 += bf_lo(u7.y); a3 += bf_hi(u7.y);
  }
  float di = dinv[node];
  float4 bv = *(const float4*)&bias[cs * 4];
  float4 o;
  o.x = a0 * di + bv.x; o.y = a1 * di + bv.y;
  o.z = a2 * di + bv.z; o.w = a3 * di + bv.w;
  o.x = o.x > 0.f ? o.x : 0.f;
  o.y = o.y > 0.f ? o.y : 0.f;
  o.z = o.z > 0.f ? o.z : 0.f;
  o.w = o.w > 0.f ? o.w : 0.f;
  *(float4*)&out[(size_t)node * 32 + cs * 4] = o;
}

// ---------------- launcher ----------------

extern "C" void kernel_launch(void* const* d_in, const int* in_sizes, int n_in,
                              void* d_out, int out_size, void* d_ws, size_t ws_size,
                              hipStream_t stream) {
  const float* x = (const float*)d_in[0];
  const int* ei = (const int*)d_in[1];
  const float* W1 = (const float*)d_in[2];
  const float* b1 = (const float*)d_in[3];
  const float* W2 = (const float*)d_in[4];
  const float* b2 = (const float*)d_in[5];

  const int N = in_sizes[0] / 128;
  const int E = in_sizes[1] / 2;
  const int* src = ei;
  const int* dst = ei + E;
  const int nb = (N + BSPAN - 1) >> BSHIFT;  // # coarse buckets (196 @ N=100K)

  char* p = (char*)d_ws;
  auto take = [&](size_t bytes) -> char* {
    char* q = p;
    p += (bytes + 255) & ~(size_t)255;
    return q;
  };
  int* bins = (int*)take((size_t)NB_MAX * CAP * 4);
  int* tail = (int*)take(NB_MAX * 4);
  unsigned* wdesc = (unsigned*)take((size_t)N * 4);
  int* col = (int*)take((size_t)nb * CAP2 * 4);
  float* dinv = (float*)take((size_t)N * 4);
  u16* g1 = (u16*)take((size_t)(N + 1) * 64 * 2);  // +1 zero row
  float* h = (float*)take((size_t)N * 64 * 4);
  u16* g2 = (u16*)take((size_t)(N + 1) * 32 * 2);  // +1 zero row

  hipMemsetAsync(tail, 0, NB_MAX * 4, stream);

  binpass<<<(E + EPBB - 1) / EPBB, BLK, 0, stream>>>(src, dst, E, bins, tail);
  bucket_sort<<<nb, BLK, 0, stream>>>(bins, tail, wdesc, col, dinv, N);

  gemm_mfma<128, 64, 2><<<(N + 127) / 128, BLK, 0, stream>>>(x, W1, dinv, g1, N);
  agg1_kernel<<<(N + 15) / 16, BLK, 0, stream>>>(g1, wdesc, col, dinv, b1, h, N);
  gemm_mfma<64, 32, 1><<<(N + 63) / 64, BLK, 0, stream>>>(h, W2, dinv, g2, N);
  agg2_kernel<<<(N + 31) / 32, BLK, 0, stream>>>(g2, wdesc, col, dinv, b2, (float*)d_out, N);
}